// Round 9
// baseline (1101.491 us; speedup 1.0000x reference)
//
#include <hip/hip_runtime.h>
#include <hip/hip_bf16.h>
#include <cfloat>

#define Nn 2048
#define KK 20
#define BB 8
#define SLOPE 0.2f
#define NCH 32   // partial chunks in global conv (8 nblk x 4 waves)

typedef __bf16 bf16x8 __attribute__((ext_vector_type(8)));
typedef float f32x4 __attribute__((ext_vector_type(4)));
typedef unsigned long long u64;

// ---------------- fused prep: wstack W1..W4 + bf16(Wg) ----------------
__device__ __forceinline__ void wstack_elem(const float* W, float* Wstk,
                                            int Co, int C, int i) {
    int o = i / C, c = i - o * C;
    float a = W[(long)o * 2 * C + c];
    float bb = W[(long)o * 2 * C + C + c];
    Wstk[(long)c * 2 * Co + o] = a;
    Wstk[(long)c * 2 * Co + Co + o] = bb - a;
}

__global__ void prep_kernel(const float* __restrict__ W1, const float* __restrict__ W2,
                            const float* __restrict__ W3, const float* __restrict__ W4,
                            const float* __restrict__ Wg,
                            float* __restrict__ ws1, float* __restrict__ ws2,
                            float* __restrict__ ws3, float* __restrict__ ws4,
                            __hip_bfloat16* __restrict__ Wgb) {
    int i = blockIdx.x * 256 + threadIdx.x;
    if (i < 192) { wstack_elem(W1, ws1, 64, 3, i); return; }
    i -= 192;
    if (i < 4096) { wstack_elem(W2, ws2, 64, 64, i); return; }
    i -= 4096;
    if (i < 8192) { wstack_elem(W3, ws3, 128, 64, i); return; }
    i -= 8192;
    if (i < 32768) { wstack_elem(W4, ws4, 256, 128, i); return; }
    i -= 32768;
    if (i < 1024 * 512) Wgb[i] = __float2bfloat16(Wg[i]);
}

// ---------------- per-point squared norm: xx[b][j] = sum_c x[c][j]^2 ----------------
__global__ void sqnorm_kernel(const float* __restrict__ x, long bst, int C,
                              float* __restrict__ xx) {
    int gid = blockIdx.x * 256 + threadIdx.x;   // 0 .. BB*Nn-1
    int b = gid >> 11, j = gid & (Nn - 1);
    const float* xb = x + (long)b * bst + j;
    float a = 0.f;
    for (int c = 0; c < C; ++c) {
        float v = xb[(long)c * Nn];
        a = fmaf(v, v, a);
    }
    xx[gid] = a;
}

// order-preserving float-bits -> u32 map (works for negatives)
__device__ __forceinline__ unsigned fkey(float f) {
    unsigned u = __float_as_uint(f);
    return u ^ (((unsigned)((int)u >> 31)) | 0x80000000u);
}

// ---------------- hi/lo bf16 split, transposed: S[b][j][0:C)=hi, [C:2C)=lo ----------
template<int C>
__global__ void __launch_bounds__(256)
split_kernel(const float* __restrict__ x, long bst, __hip_bfloat16* __restrict__ S) {
    __shared__ __bf16 t[64][2 * C + 2];   // +2 pad: u32 row stride C+1 (odd) -> 2-way max
    const int tid = threadIdx.x;
    const int b = blockIdx.x >> 5;
    const int j0 = (blockIdx.x & 31) * 64;
    const int jl = tid & 63, cg = tid >> 6;
    const float* xb = x + (long)b * bst;
    for (int c = cg; c < C; c += 4) {
        float v = xb[(long)c * Nn + j0 + jl];
        __bf16 h = (__bf16)v;
        float l = v - (float)h;
        t[jl][c] = h;
        t[jl][C + c] = (__bf16)l;
    }
    __syncthreads();
    const unsigned* src = (const unsigned*)&t[0][0];
    unsigned* dst = (unsigned*)(S + ((long)b * 2048 + j0) * (2 * C));
    for (int i = tid; i < 64 * C; i += 256) {
        int row = i / C, col = i - row * C;
        dst[i] = src[row * (C + 1) + col];
    }
}

// ---------------- KNN via MFMA Gram + fused selection ----------------
// block: 8 centers x full 2048 j; 512 thr = 8 waves (wave = 256-j strip).
// dot = h.h + h.l + l.h  (K=3C over S with per-segment offsets).
template<int C>
__global__ void __launch_bounds__(512)
gram_knn(const __hip_bfloat16* __restrict__ S, const float* __restrict__ xx,
         int* __restrict__ idx) {
    constexpr int SK = 2 * C;
    constexpr int KCH = C / 32;
    __shared__ unsigned dist[8][2048];   // 64 KB
    const int tid = threadIdx.x;
    const int w = tid >> 6, lane = tid & 63;
    const int lm = lane & 15, quad = lane >> 4;
    const int b  = blockIdx.x & 7;          // XCD-swizzle: batch b pinned per XCD
    const int n0 = (blockIdx.x >> 3) * 8;
    const __hip_bfloat16* Sb = S + (long)b * 2048 * SK;
    const float* xxb = xx + (long)b * Nn;

    // A frags: 8 real centers; rows 8-15 duplicate rows 0-7 (discarded)
    bf16x8 afr[3 * KCH];
    {
        const __hip_bfloat16* Arow = Sb + (long)(n0 + (lm & 7)) * SK + quad * 8;
        const int segA[3] = {0, 0, C};
        #pragma unroll
        for (int s = 0; s < 3; ++s)
            #pragma unroll
            for (int kc = 0; kc < KCH; ++kc)
                afr[s * KCH + kc] = *(const bf16x8*)(const void*)(Arow + segA[s] + kc * 32);
    }
    const int segB[3] = {0, C, 0};
    const int j0w = w * 256;
    for (int jt = 0; jt < 16; ++jt) {
        const int j0 = j0w + jt * 16;
        const __hip_bfloat16* Brow = Sb + (long)(j0 + lm) * SK + quad * 8;
        f32x4 acc = {0.f, 0.f, 0.f, 0.f};
        #pragma unroll
        for (int s = 0; s < 3; ++s)
            #pragma unroll
            for (int kc = 0; kc < KCH; ++kc) {
                bf16x8 bf = *(const bf16x8*)(const void*)(Brow + segB[s] + kc * 32);
                acc = __builtin_amdgcn_mfma_f32_16x16x32_bf16(afr[s * KCH + kc], bf, acc, 0, 0, 0);
            }
        // D: col(j-local) = lane&15, row(m) = quad*4 + r ; keep rows 0-7
        if (quad < 2) {
            float xxv = xxb[j0 + lm];
            #pragma unroll
            for (int r = 0; r < 4; ++r)
                dist[quad * 4 + r][j0 + lm] = fkey(fmaf(-2.f, acc[r], xxv));
        }
    }
    __syncthreads();

    // selection: wave w owns row w; lazy per-lane top-2 in registers.
    unsigned* drow = dist[w];
    int* outp = idx + ((long)b * Nn + n0 + w) * KK;

    auto scan2 = [&](u64& m1, u64& m2) {
        m1 = ~0ull; m2 = ~0ull;
        #pragma unroll
        for (int jj = 0; jj < 8; ++jj) {
            int j4 = (jj * 64 + lane) * 4;
            uint4 v = *(const uint4*)(drow + j4);
            u64 kk0 = ((u64)v.x << 32) | (unsigned)(j4 + 0);
            u64 kk1 = ((u64)v.y << 32) | (unsigned)(j4 + 1);
            u64 kk2 = ((u64)v.z << 32) | (unsigned)(j4 + 2);
            u64 kk3 = ((u64)v.w << 32) | (unsigned)(j4 + 3);
            u64 hi;
            hi = kk0 > m1 ? kk0 : m1; m1 = kk0 < m1 ? kk0 : m1; m2 = hi < m2 ? hi : m2;
            hi = kk1 > m1 ? kk1 : m1; m1 = kk1 < m1 ? kk1 : m1; m2 = hi < m2 ? hi : m2;
            hi = kk2 > m1 ? kk2 : m1; m1 = kk2 < m1 ? kk2 : m1; m2 = hi < m2 ? hi : m2;
            hi = kk3 > m1 ? kk3 : m1; m1 = kk3 < m1 ? kk3 : m1; m2 = hi < m2 ? hi : m2;
        }
    };

    u64 lm1, lm2;
    scan2(lm1, lm2);
    for (int k = 0; k < KK; ++k) {
        unsigned key = (unsigned)(lm1 >> 32);
        unsigned bk = key;
        #pragma unroll
        for (int s = 1; s < 64; s <<= 1) {
            unsigned ob = __shfl_xor(bk, s, 64);
            bk = ob < bk ? ob : bk;
        }
        u64 winners = __ballot(key == bk);
        int wl; int bi;
        if (__popcll(winners) == 1) {
            wl = (int)(__ffsll((unsigned long long)winners) - 1);
            bi = (int)__shfl((unsigned)lm1, wl, 64);
        } else {
            unsigned jc = (key == bk) ? (unsigned)lm1 : 0xFFFFFFFFu;
            unsigned bj = jc;
            #pragma unroll
            for (int s = 1; s < 64; s <<= 1) {
                unsigned oj = __shfl_xor(bj, s, 64);
                bj = oj < bj ? oj : bj;
            }
            winners = __ballot(key == bk && (unsigned)lm1 == bj);
            wl = (int)(__ffsll((unsigned long long)winners) - 1);
            bi = (int)bj;
        }
        if (lane == 0) outp[k] = bi;
        if (lane == wl) {
            drow[bi] = 0xFFFFFFFFu;
            if (lm2 != ~0ull) { lm1 = lm2; lm2 = ~0ull; }
            else scan2(lm1, lm2);
        }
    }
}

// ---------------- stage-1 KNN (C=3): fused fp32, 8 rows/block ----------------
template<int C>
__global__ void __launch_bounds__(512)
knn_kernel(const float* __restrict__ x, long bstride,
           const float* __restrict__ xx, int* __restrict__ idx) {
    __shared__ unsigned dist[8][Nn];
    const int tid = threadIdx.x;
    const int b  = blockIdx.x >> 8;
    const int n0 = (blockIdx.x & 255) * 8;
    const float* xb = x + (long)b * bstride;
    const float* xxb = xx + (long)b * Nn;

    float acc[8][4];
    #pragma unroll
    for (int r = 0; r < 8; ++r)
        #pragma unroll
        for (int q = 0; q < 4; ++q) acc[r][q] = 0.f;

    #pragma unroll
    for (int c = 0; c < C; ++c) {
        const float* xp = xb + (long)c * Nn;
        float xv0 = xp[tid];
        float xv1 = xp[tid + 512];
        float xv2 = xp[tid + 1024];
        float xv3 = xp[tid + 1536];
        float4 c0 = *(const float4*)(xp + n0);
        float4 c1 = *(const float4*)(xp + n0 + 4);
        acc[0][0] += c0.x * xv0; acc[0][1] += c0.x * xv1; acc[0][2] += c0.x * xv2; acc[0][3] += c0.x * xv3;
        acc[1][0] += c0.y * xv0; acc[1][1] += c0.y * xv1; acc[1][2] += c0.y * xv2; acc[1][3] += c0.y * xv3;
        acc[2][0] += c0.z * xv0; acc[2][1] += c0.z * xv1; acc[2][2] += c0.z * xv2; acc[2][3] += c0.z * xv3;
        acc[3][0] += c0.w * xv0; acc[3][1] += c0.w * xv1; acc[3][2] += c0.w * xv2; acc[3][3] += c0.w * xv3;
        acc[4][0] += c1.x * xv0; acc[4][1] += c1.x * xv1; acc[4][2] += c1.x * xv2; acc[4][3] += c1.x * xv3;
        acc[5][0] += c1.y * xv0; acc[5][1] += c1.y * xv1; acc[5][2] += c1.y * xv2; acc[5][3] += c1.y * xv3;
        acc[6][0] += c1.z * xv0; acc[6][1] += c1.z * xv1; acc[6][2] += c1.z * xv2; acc[6][3] += c1.z * xv3;
        acc[7][0] += c1.w * xv0; acc[7][1] += c1.w * xv1; acc[7][2] += c1.w * xv2; acc[7][3] += c1.w * xv3;
    }
    float xq0 = xxb[tid], xq1 = xxb[tid + 512], xq2 = xxb[tid + 1024], xq3 = xxb[tid + 1536];
    #pragma unroll
    for (int r = 0; r < 8; ++r) {
        dist[r][tid]        = fkey(fmaf(-2.f, acc[r][0], xq0));
        dist[r][tid + 512]  = fkey(fmaf(-2.f, acc[r][1], xq1));
        dist[r][tid + 1024] = fkey(fmaf(-2.f, acc[r][2], xq2));
        dist[r][tid + 1536] = fkey(fmaf(-2.f, acc[r][3], xq3));
    }
    __syncthreads();

    const int w = tid >> 6, lane = tid & 63;
    unsigned* drow = dist[w];
    int* outp = idx + ((long)b * Nn + n0 + w) * KK;

    auto scan2 = [&](u64& m1, u64& m2) {
        m1 = ~0ull; m2 = ~0ull;
        #pragma unroll
        for (int jj = 0; jj < 8; ++jj) {
            int j4 = (jj * 64 + lane) * 4;
            uint4 v = *(const uint4*)(drow + j4);
            u64 kk0 = ((u64)v.x << 32) | (unsigned)(j4 + 0);
            u64 kk1 = ((u64)v.y << 32) | (unsigned)(j4 + 1);
            u64 kk2 = ((u64)v.z << 32) | (unsigned)(j4 + 2);
            u64 kk3 = ((u64)v.w << 32) | (unsigned)(j4 + 3);
            u64 hi;
            hi = kk0 > m1 ? kk0 : m1; m1 = kk0 < m1 ? kk0 : m1; m2 = hi < m2 ? hi : m2;
            hi = kk1 > m1 ? kk1 : m1; m1 = kk1 < m1 ? kk1 : m1; m2 = hi < m2 ? hi : m2;
            hi = kk2 > m1 ? kk2 : m1; m1 = kk2 < m1 ? kk2 : m1; m2 = hi < m2 ? hi : m2;
            hi = kk3 > m1 ? kk3 : m1; m1 = kk3 < m1 ? kk3 : m1; m2 = hi < m2 ? hi : m2;
        }
    };

    u64 lm1, lm2;
    scan2(lm1, lm2);
    for (int k = 0; k < KK; ++k) {
        unsigned key = (unsigned)(lm1 >> 32);
        unsigned bk = key;
        #pragma unroll
        for (int s = 1; s < 64; s <<= 1) {
            unsigned ob = __shfl_xor(bk, s, 64);
            bk = ob < bk ? ob : bk;
        }
        u64 winners = __ballot(key == bk);
        int wl; int bi;
        if (__popcll(winners) == 1) {
            wl = (int)(__ffsll((unsigned long long)winners) - 1);
            bi = (int)__shfl((unsigned)lm1, wl, 64);
        } else {
            unsigned jc = (key == bk) ? (unsigned)lm1 : 0xFFFFFFFFu;
            unsigned bj = jc;
            #pragma unroll
            for (int s = 1; s < 64; s <<= 1) {
                unsigned oj = __shfl_xor(bj, s, 64);
                bj = oj < bj ? oj : bj;
            }
            winners = __ballot(key == bk && (unsigned)lm1 == bj);
            wl = (int)(__ffsll((unsigned long long)winners) - 1);
            bi = (int)bj;
        }
        if (lane == 0) outp[k] = bi;
        if (lane == wl) {
            drow[bi] = 0xFFFFFFFFu;
            if (lm2 != ~0ull) { lm1 = lm2; lm2 = ~0ull; }
            else scan2(lm1, lm2);
        }
    }
}

// ---------------- projection GEMM: Z[m][0..2Co) = sum_c x[c][m] * Wstk[c][.] ----
template<int CIN, int CO2>
__global__ void __launch_bounds__(256)
proj_gemm(const float* __restrict__ x, long bst,
          const float* __restrict__ Wstk, float* __restrict__ Z) {
    const int tid = threadIdx.x;
    const int b  = blockIdx.x & 7;
    const int mt = (blockIdx.x >> 3) & 31;
    const int ot = blockIdx.x >> 8;
    const int mi = mt * 64 + (tid & 15) * 4;
    const int oj = ot * 64 + (tid >> 4) * 4;
    const float* xb = x + (long)b * bst + mi;

    float acc[4][4];
    #pragma unroll
    for (int r = 0; r < 4; ++r)
        #pragma unroll
        for (int j = 0; j < 4; ++j) acc[r][j] = 0.f;

    #pragma unroll 4
    for (int c = 0; c < CIN; ++c) {
        float4 xv = *(const float4*)(xb + (long)c * Nn);
        float4 wv = *(const float4*)(Wstk + (long)c * CO2 + oj);
        acc[0][0] += xv.x * wv.x; acc[0][1] += xv.x * wv.y; acc[0][2] += xv.x * wv.z; acc[0][3] += xv.x * wv.w;
        acc[1][0] += xv.y * wv.x; acc[1][1] += xv.y * wv.y; acc[1][2] += xv.y * wv.z; acc[1][3] += xv.y * wv.w;
        acc[2][0] += xv.z * wv.x; acc[2][1] += xv.z * wv.y; acc[2][2] += xv.z * wv.z; acc[2][3] += xv.z * wv.w;
        acc[3][0] += xv.w * wv.x; acc[3][1] += xv.w * wv.y; acc[3][2] += xv.w * wv.z; acc[3][3] += xv.w * wv.w;
    }
    float* Zb = Z + (long)b * 2048 * CO2;
    #pragma unroll
    for (int r = 0; r < 4; ++r) {
        float4 v = make_float4(acc[r][0], acc[r][1], acc[r][2], acc[r][3]);
        *(float4*)(Zb + (long)(mi + r) * CO2 + oj) = v;
    }
}

// ---------------- gather-max epilogue (also emits bf16 n-major copy) ----------------
template<int CO>
__global__ void __launch_bounds__(256)
gather_max(const float* __restrict__ Z, const int* __restrict__ idx,
           float* __restrict__ out, long obst,
           __hip_bfloat16* __restrict__ xbT, int coff) {
    constexpr int CO2 = 2 * CO;
    constexpr int VEC = CO / 64;
    __shared__ float tile[16][CO + 4];
    __shared__ int ji[16][KK];
    const int tid = threadIdx.x;
    const int b  = blockIdx.x & 7;
    const int n0 = (blockIdx.x >> 3) * 16;
    const float* Zb = Z + (long)b * 2048 * CO2;

    for (int t = tid; t < 16 * KK; t += 256) {
        int nn = t / KK, k = t - nn * KK;
        ji[nn][k] = idx[((long)b * Nn + n0 + nn) * KK + k];
    }
    __syncthreads();

    const int w = tid >> 6, lane = tid & 63;
    for (int i = 0; i < 4; ++i) {
        int nl = w * 4 + i, n = n0 + nl;
        float mx[VEC];
        #pragma unroll
        for (int v = 0; v < VEC; ++v) mx[v] = -FLT_MAX;
        for (int k = 0; k < KK; ++k) {
            int m = ji[nl][k];
            const float* zr = Zb + (long)m * CO2 + lane * VEC;
            #pragma unroll
            for (int v = 0; v < VEC; ++v) mx[v] = fmaxf(mx[v], zr[v]);
        }
        const float* zc = Zb + (long)n * CO2 + CO + lane * VEC;
        __hip_bfloat16* xr = xbT + ((long)b * 2048 + n) * 512 + coff + lane * VEC;
        #pragma unroll
        for (int v = 0; v < VEC; ++v) {
            float y = mx[v] + zc[v];
            y = y > 0.f ? y : SLOPE * y;
            tile[nl][lane * VEC + v] = y;
            xr[v] = __float2bfloat16(y);
        }
    }
    __syncthreads();

    for (int r = tid; r < CO * 4; r += 256) {
        int o = r >> 2, q = r & 3;
        float4 vv;
        vv.x = tile[q * 4 + 0][o];
        vv.y = tile[q * 4 + 1][o];
        vv.z = tile[q * 4 + 2][o];
        vv.w = tile[q * 4 + 3][o];
        *(float4*)(out + (long)b * obst + (long)o * Nn + n0 + q * 4) = vv;
    }
}

// ---------------- Global conv via bf16 MFMA, fused max-over-n ----------------
__global__ void __launch_bounds__(256)
global_mfma(const __hip_bfloat16* __restrict__ Wgb,   // [1024][512]
            const __hip_bfloat16* __restrict__ xbT,   // [B][2048][512]
            float* __restrict__ partial) {            // [B][1024][NCH]
    const int tid = threadIdx.x;
    const int w = tid >> 6, lane = tid & 63;
    const int lm = lane & 15, quad = lane >> 4;
    const int b  = blockIdx.x >> 7;
    const int ot = (blockIdx.x >> 3) & 15;
    const int nb = blockIdx.x & 7;
    const int o0 = ot * 64;
    const int nbw = nb * 256 + w * 64;

    const __hip_bfloat16* Arow = Wgb + (long)(o0 + lm) * 512 + quad * 8;
    const __hip_bfloat16* Brow = xbT + ((long)b * 2048 + nbw + lm) * 512 + quad * 8;

    f32x4 acc[4][4];
    #pragma unroll
    for (int mt = 0; mt < 4; ++mt)
        #pragma unroll
        for (int nt = 0; nt < 4; ++nt)
            acc[mt][nt] = (f32x4){0.f, 0.f, 0.f, 0.f};

    #pragma unroll 2
    for (int kk = 0; kk < 512; kk += 32) {
        bf16x8 a[4], bb[4];
        #pragma unroll
        for (int mt = 0; mt < 4; ++mt)
            a[mt] = *(const bf16x8*)(const void*)(Arow + (long)mt * 16 * 512 + kk);
        #pragma unroll
        for (int nt = 0; nt < 4; ++nt)
            bb[nt] = *(const bf16x8*)(const void*)(Brow + (long)nt * 16 * 512 + kk);
        #pragma unroll
        for (int mt = 0; mt < 4; ++mt)
            #pragma unroll
            for (int nt = 0; nt < 4; ++nt)
                acc[mt][nt] = __builtin_amdgcn_mfma_f32_16x16x32_bf16(
                    a[mt], bb[nt], acc[mt][nt], 0, 0, 0);
    }

    #pragma unroll
    for (int mt = 0; mt < 4; ++mt) {
        #pragma unroll
        for (int r = 0; r < 4; ++r) {
            float v = fmaxf(fmaxf(acc[mt][0][r], acc[mt][1][r]),
                            fmaxf(acc[mt][2][r], acc[mt][3][r]));
            #pragma unroll
            for (int s = 1; s < 16; s <<= 1)
                v = fmaxf(v, __shfl_xor(v, s, 16));
            if (lm == 0) {
                int o = o0 + mt * 16 + quad * 4 + r;
                partial[((long)b * 1024 + o) * NCH + nb * 4 + w] = v;
            }
        }
    }
}

// ---------------- final max over chunks + leaky ----------------
__global__ void gmax_kernel(const float* __restrict__ partial, float* __restrict__ out) {
    int i = blockIdx.x * 256 + threadIdx.x;   // 0..8191
    float m = -FLT_MAX;
    #pragma unroll
    for (int j = 0; j < NCH; ++j) m = fmaxf(m, partial[(long)i * NCH + j]);
    out[i] = m > 0.f ? m : SLOPE * m;
}

extern "C" void kernel_launch(void* const* d_in, const int* in_sizes, int n_in,
                              void* d_out, int out_size, void* d_ws, size_t ws_size,
                              hipStream_t stream) {
    const float* x  = (const float*)d_in[0];
    const float* W1 = (const float*)d_in[1];   // [64][6]
    const float* W2 = (const float*)d_in[2];   // [64][128]
    const float* W3 = (const float*)d_in[3];   // [128][128]
    const float* W4 = (const float*)d_in[4];   // [256][256]
    const float* Wg = (const float*)d_in[5];   // [1024][512]
    float* out = (float*)d_out;

    float* ws = (float*)d_ws;
    float* xcat = ws;                                       // 8*512*2048 f32
    int*   idxb = (int*)(xcat + (long)BB * 512 * Nn);       // 8*2048*20 int
    float* part = (float*)(idxb + (long)BB * Nn * KK);      // 8*1024*NCH f32
    float* ws1  = part + (long)BB * 1024 * NCH;             // 3*128
    float* ws2  = ws1 + 3 * 128;                            // 64*128
    float* ws3  = ws2 + 64 * 128;                           // 64*256
    float* ws4  = ws3 + 64 * 256;                           // 128*512
    __hip_bfloat16* Wgb = (__hip_bfloat16*)(ws4 + 128 * 512);   // 1024*512 bf16
    __hip_bfloat16* xbT = Wgb + (long)1024 * 512;               // 8*2048*512 bf16
    float* Z    = (float*)(xbT + (long)BB * Nn * 512);          // 8*2048*512 f32
    float* xx   = Z + (long)BB * Nn * 512;                      // 8*2048 f32
    __hip_bfloat16* S = (__hip_bfloat16*)Z;   // split buffer aliases Z (disjoint in time)

    const long XB = (long)512 * Nn;   // xcat batch stride

    prep_kernel<<<(192 + 4096 + 8192 + 32768 + 1024 * 512 + 255) / 256, 256, 0, stream>>>(
        W1, W2, W3, W4, Wg, ws1, ws2, ws3, ws4, Wgb);

    const int knn_grid  = BB * 256;        // stage-1 fused knn
    const int gram_grid = BB * 256;        // 2048 blocks, 512 thr
    const int spl_grid  = BB * 32;         // 256 blocks
    const int sq_grid   = BB * Nn / 256;   // 64
    const int ep_grid   = (Nn / 16) * BB;  // 1024

    // stage 1: x (C=3) -> xcat[0:64], xbT[:, 0:64)
    sqnorm_kernel<<<sq_grid, 256, 0, stream>>>(x, (long)3 * Nn, 3, xx);
    knn_kernel<3><<<knn_grid, 512, 0, stream>>>(x, (long)3 * Nn, xx, idxb);
    proj_gemm<3, 128><<<8 * 32 * 2, 256, 0, stream>>>(x, (long)3 * Nn, ws1, Z);
    gather_max<64><<<ep_grid, 256, 0, stream>>>(Z, idxb, xcat, XB, xbT, 0);
    // stage 2
    sqnorm_kernel<<<sq_grid, 256, 0, stream>>>(xcat, XB, 64, xx);
    split_kernel<64><<<spl_grid, 256, 0, stream>>>(xcat, XB, S);
    gram_knn<64><<<gram_grid, 512, 0, stream>>>(S, xx, idxb);
    proj_gemm<64, 128><<<8 * 32 * 2, 256, 0, stream>>>(xcat, XB, ws2, Z);
    gather_max<64><<<ep_grid, 256, 0, stream>>>(Z, idxb, xcat + (long)64 * Nn, XB, xbT, 64);
    // stage 3
    sqnorm_kernel<<<sq_grid, 256, 0, stream>>>(xcat + (long)64 * Nn, XB, 64, xx);
    split_kernel<64><<<spl_grid, 256, 0, stream>>>(xcat + (long)64 * Nn, XB, S);
    gram_knn<64><<<gram_grid, 512, 0, stream>>>(S, xx, idxb);
    proj_gemm<64, 256><<<8 * 32 * 4, 256, 0, stream>>>(xcat + (long)64 * Nn, XB, ws3, Z);
    gather_max<128><<<ep_grid, 256, 0, stream>>>(Z, idxb, xcat + (long)128 * Nn, XB, xbT, 128);
    // stage 4
    sqnorm_kernel<<<sq_grid, 256, 0, stream>>>(xcat + (long)128 * Nn, XB, 128, xx);
    split_kernel<128><<<spl_grid, 256, 0, stream>>>(xcat + (long)128 * Nn, XB, S);
    gram_knn<128><<<gram_grid, 512, 0, stream>>>(S, xx, idxb);
    proj_gemm<128, 512><<<8 * 32 * 8, 256, 0, stream>>>(xcat + (long)128 * Nn, XB, ws4, Z);
    gather_max<256><<<ep_grid, 256, 0, stream>>>(Z, idxb, xcat + (long)256 * Nn, XB, xbT, 256);

    // global conv via MFMA (fused max) + final reduce
    global_mfma<<<BB * 16 * 8, 256, 0, stream>>>(Wgb, xbT, part);
    gmax_kernel<<<BB * 1024 / 256, 256, 0, stream>>>(part, out);
}

// Round 10
// 833.536 us; speedup vs baseline: 1.3215x; 1.3215x over previous
//
#include <hip/hip_runtime.h>
#include <hip/hip_bf16.h>
#include <cfloat>

#define Nn 2048
#define KK 20
#define BB 8
#define SLOPE 0.2f
#define NCH 32   // partial chunks in global conv (8 nblk x 4 waves)

typedef __bf16 bf16x8 __attribute__((ext_vector_type(8)));
typedef float f32x4 __attribute__((ext_vector_type(4)));
typedef unsigned long long u64;

// ---------------- fused prep: wstack W1..W4 + bf16(Wg) ----------------
__device__ __forceinline__ void wstack_elem(const float* W, float* Wstk,
                                            int Co, int C, int i) {
    int o = i / C, c = i - o * C;
    float a = W[(long)o * 2 * C + c];
    float bb = W[(long)o * 2 * C + C + c];
    Wstk[(long)c * 2 * Co + o] = a;
    Wstk[(long)c * 2 * Co + Co + o] = bb - a;
}

__global__ void prep_kernel(const float* __restrict__ W1, const float* __restrict__ W2,
                            const float* __restrict__ W3, const float* __restrict__ W4,
                            const float* __restrict__ Wg,
                            float* __restrict__ ws1, float* __restrict__ ws2,
                            float* __restrict__ ws3, float* __restrict__ ws4,
                            __hip_bfloat16* __restrict__ Wgb) {
    int i = blockIdx.x * 256 + threadIdx.x;
    if (i < 192) { wstack_elem(W1, ws1, 64, 3, i); return; }
    i -= 192;
    if (i < 4096) { wstack_elem(W2, ws2, 64, 64, i); return; }
    i -= 4096;
    if (i < 8192) { wstack_elem(W3, ws3, 128, 64, i); return; }
    i -= 8192;
    if (i < 32768) { wstack_elem(W4, ws4, 256, 128, i); return; }
    i -= 32768;
    if (i < 1024 * 512) Wgb[i] = __float2bfloat16(Wg[i]);
}

// ---------------- per-point squared norm ----------------
__global__ void sqnorm_kernel(const float* __restrict__ x, long bst, int C,
                              float* __restrict__ xx) {
    int gid = blockIdx.x * 256 + threadIdx.x;
    int b = gid >> 11, j = gid & (Nn - 1);
    const float* xb = x + (long)b * bst + j;
    float a = 0.f;
    for (int c = 0; c < C; ++c) {
        float v = xb[(long)c * Nn];
        a = fmaf(v, v, a);
    }
    xx[gid] = a;
}

// order-preserving float-bits -> u32 map
__device__ __forceinline__ unsigned fkey(float f) {
    unsigned u = __float_as_uint(f);
    return u ^ (((unsigned)((int)u >> 31)) | 0x80000000u);
}

// ---------------- hi/lo bf16 split, transposed: S[b][j][0:C)=hi, [C:2C)=lo ----------
template<int C>
__global__ void __launch_bounds__(256)
split_kernel(const float* __restrict__ x, long bst, __hip_bfloat16* __restrict__ S) {
    __shared__ __bf16 t[64][2 * C + 2];
    const int tid = threadIdx.x;
    const int b = blockIdx.x >> 5;
    const int j0 = (blockIdx.x & 31) * 64;
    const int jl = tid & 63, cg = tid >> 6;
    const float* xb = x + (long)b * bst;
    for (int c = cg; c < C; c += 4) {
        float v = xb[(long)c * Nn + j0 + jl];
        __bf16 h = (__bf16)v;
        float l = v - (float)h;
        t[jl][c] = h;
        t[jl][C + c] = (__bf16)l;
    }
    __syncthreads();
    const unsigned* src = (const unsigned*)&t[0][0];
    unsigned* dst = (unsigned*)(S + ((long)b * 2048 + j0) * (2 * C));
    for (int i = tid; i < 64 * C; i += 256) {
        int row = i / C, col = i - row * C;
        dst[i] = src[row * (C + 1) + col];
    }
}

// ---------------- Gram GEMM: keys[n][j] = fkey(xx_j - 2*dot) ----------------
// block: 256 centers x 64 j; 4 waves (wave = 64 centers x 64 j, 4x4 MFMA tiles).
// B strip staged in LDS (coalesced contiguous rows, +16B pad); A gathered from L2.
// dot = hh + hl + lh over split buffer (same order as R9 -> bit-identical keys).
template<int C>
__global__ void __launch_bounds__(256)
gram_gemm(const __hip_bfloat16* __restrict__ S, const float* __restrict__ xx,
          unsigned* __restrict__ Dk, int bbase) {
    constexpr int SK = 2 * C;                 // bf16 per row
    constexpr int RS16 = SK / 8;              // uint4 per row
    constexpr int STRIDE = SK * 2 + 16;       // LDS row stride (bytes)
    constexpr int KCH = C / 32;
    __shared__ unsigned char Bs[64 * STRIDE];
    const int tid = threadIdx.x;
    const int w = tid >> 6, lane = tid & 63;
    const int lm = lane & 15, quad = lane >> 4;
    const int bi = blockIdx.x & 3;            // batch within pass
    const int ct = (blockIdx.x >> 2) & 7;
    const int jt = blockIdx.x >> 5;
    const int b  = bbase + bi;
    const int j0 = jt * 64;
    const int c0w = ct * 256 + w * 64;
    const __hip_bfloat16* Sb = S + (long)b * 2048 * SK;

    // stage B rows [j0, j0+64) — contiguous per row, fully coalesced
    {
        const uint4* src = (const uint4*)(Sb + (long)j0 * SK);
        #pragma unroll
        for (int i = 0; i < (64 * RS16) / 256; ++i) {
            int idx = tid + i * 256;
            int row = idx / RS16, ch = idx - row * RS16;
            uint4 v = src[idx];
            *(uint4*)(Bs + row * STRIDE + ch * 16) = v;
        }
    }
    __syncthreads();

    f32x4 acc[4][4];
    #pragma unroll
    for (int mt = 0; mt < 4; ++mt)
        #pragma unroll
        for (int nt = 0; nt < 4; ++nt)
            acc[mt][nt] = (f32x4){0.f, 0.f, 0.f, 0.f};

    const int segA[3] = {0, 0, C};
    const int segB[3] = {0, C, 0};
    #pragma unroll
    for (int s = 0; s < 3; ++s) {
        #pragma unroll
        for (int kc = 0; kc < KCH; ++kc) {
            const int ka = segA[s] + kc * 32 + quad * 8;
            const int kb = (segB[s] + kc * 32 + quad * 8) * 2;  // bytes
            bf16x8 a[4], bfr[4];
            #pragma unroll
            for (int mt = 0; mt < 4; ++mt)
                a[mt] = *(const bf16x8*)(const void*)(Sb + (long)(c0w + mt * 16 + lm) * SK + ka);
            #pragma unroll
            for (int nt = 0; nt < 4; ++nt)
                bfr[nt] = *(const bf16x8*)(const void*)(Bs + (nt * 16 + lm) * STRIDE + kb);
            #pragma unroll
            for (int mt = 0; mt < 4; ++mt)
                #pragma unroll
                for (int nt = 0; nt < 4; ++nt)
                    acc[mt][nt] = __builtin_amdgcn_mfma_f32_16x16x32_bf16(
                        a[mt], bfr[nt], acc[mt][nt], 0, 0, 0);
        }
    }

    // epilogue: D col(j)=lane&15, row(m)=quad*4+r
    unsigned* Dkb = Dk + (long)bi * 2048 * 2048;
    #pragma unroll
    for (int nt = 0; nt < 4; ++nt) {
        int j = j0 + nt * 16 + lm;
        float xxv = xx[(long)b * Nn + j];
        #pragma unroll
        for (int mt = 0; mt < 4; ++mt) {
            #pragma unroll
            for (int r = 0; r < 4; ++r) {
                int m = c0w + mt * 16 + quad * 4 + r;
                Dkb[(long)m * 2048 + j] = fkey(fmaf(-2.f, acc[mt][nt][r], xxv));
            }
        }
    }
}

// ---------------- selection over precomputed keys: 4 rows/block ----------------
__global__ void __launch_bounds__(256)
knn_select(const unsigned* __restrict__ Dk, int bbase, int* __restrict__ idx) {
    __shared__ unsigned dist[4][2048];   // 32 KB
    const int tid = threadIdx.x;
    const int bi = blockIdx.x & 3;
    const int n0 = (blockIdx.x >> 2) * 4;
    const int b = bbase + bi;

    {
        const uint4* s4 = (const uint4*)(Dk + ((long)bi * 2048 + n0) * 2048);
        uint4* d4 = (uint4*)&dist[0][0];
        #pragma unroll
        for (int i = 0; i < 8; ++i) d4[tid + i * 256] = s4[tid + i * 256];
    }
    __syncthreads();

    const int w = tid >> 6, lane = tid & 63;
    unsigned* drow = dist[w];
    int* outp = idx + ((long)b * Nn + n0 + w) * KK;

    auto scan2 = [&](u64& m1, u64& m2) {
        m1 = ~0ull; m2 = ~0ull;
        #pragma unroll
        for (int jj = 0; jj < 8; ++jj) {
            int j4 = (jj * 64 + lane) * 4;
            uint4 v = *(const uint4*)(drow + j4);
            u64 kk0 = ((u64)v.x << 32) | (unsigned)(j4 + 0);
            u64 kk1 = ((u64)v.y << 32) | (unsigned)(j4 + 1);
            u64 kk2 = ((u64)v.z << 32) | (unsigned)(j4 + 2);
            u64 kk3 = ((u64)v.w << 32) | (unsigned)(j4 + 3);
            u64 hi;
            hi = kk0 > m1 ? kk0 : m1; m1 = kk0 < m1 ? kk0 : m1; m2 = hi < m2 ? hi : m2;
            hi = kk1 > m1 ? kk1 : m1; m1 = kk1 < m1 ? kk1 : m1; m2 = hi < m2 ? hi : m2;
            hi = kk2 > m1 ? kk2 : m1; m1 = kk2 < m1 ? kk2 : m1; m2 = hi < m2 ? hi : m2;
            hi = kk3 > m1 ? kk3 : m1; m1 = kk3 < m1 ? kk3 : m1; m2 = hi < m2 ? hi : m2;
        }
    };

    u64 lm1, lm2;
    scan2(lm1, lm2);
    for (int k = 0; k < KK; ++k) {
        unsigned key = (unsigned)(lm1 >> 32);
        unsigned bk = key;
        #pragma unroll
        for (int s = 1; s < 64; s <<= 1) {
            unsigned ob = __shfl_xor(bk, s, 64);
            bk = ob < bk ? ob : bk;
        }
        u64 winners = __ballot(key == bk);
        int wl; int bi2;
        if (__popcll(winners) == 1) {
            wl = (int)(__ffsll((unsigned long long)winners) - 1);
            bi2 = (int)__shfl((unsigned)lm1, wl, 64);
        } else {
            unsigned jc = (key == bk) ? (unsigned)lm1 : 0xFFFFFFFFu;
            unsigned bj = jc;
            #pragma unroll
            for (int s = 1; s < 64; s <<= 1) {
                unsigned oj = __shfl_xor(bj, s, 64);
                bj = oj < bj ? oj : bj;
            }
            winners = __ballot(key == bk && (unsigned)lm1 == bj);
            wl = (int)(__ffsll((unsigned long long)winners) - 1);
            bi2 = (int)bj;
        }
        if (lane == 0) outp[k] = bi2;
        if (lane == wl) {
            drow[bi2] = 0xFFFFFFFFu;
            if (lm2 != ~0ull) { lm1 = lm2; lm2 = ~0ull; }
            else scan2(lm1, lm2);
        }
    }
}

// ---------------- stage-1 KNN (C=3): fused fp32, 8 rows/block ----------------
template<int C>
__global__ void __launch_bounds__(512)
knn_kernel(const float* __restrict__ x, long bstride,
           const float* __restrict__ xx, int* __restrict__ idx) {
    __shared__ unsigned dist[8][Nn];
    const int tid = threadIdx.x;
    const int b  = blockIdx.x >> 8;
    const int n0 = (blockIdx.x & 255) * 8;
    const float* xb = x + (long)b * bstride;
    const float* xxb = xx + (long)b * Nn;

    float acc[8][4];
    #pragma unroll
    for (int r = 0; r < 8; ++r)
        #pragma unroll
        for (int q = 0; q < 4; ++q) acc[r][q] = 0.f;

    #pragma unroll
    for (int c = 0; c < C; ++c) {
        const float* xp = xb + (long)c * Nn;
        float xv0 = xp[tid];
        float xv1 = xp[tid + 512];
        float xv2 = xp[tid + 1024];
        float xv3 = xp[tid + 1536];
        float4 c0 = *(const float4*)(xp + n0);
        float4 c1 = *(const float4*)(xp + n0 + 4);
        acc[0][0] += c0.x * xv0; acc[0][1] += c0.x * xv1; acc[0][2] += c0.x * xv2; acc[0][3] += c0.x * xv3;
        acc[1][0] += c0.y * xv0; acc[1][1] += c0.y * xv1; acc[1][2] += c0.y * xv2; acc[1][3] += c0.y * xv3;
        acc[2][0] += c0.z * xv0; acc[2][1] += c0.z * xv1; acc[2][2] += c0.z * xv2; acc[2][3] += c0.z * xv3;
        acc[3][0] += c0.w * xv0; acc[3][1] += c0.w * xv1; acc[3][2] += c0.w * xv2; acc[3][3] += c0.w * xv3;
        acc[4][0] += c1.x * xv0; acc[4][1] += c1.x * xv1; acc[4][2] += c1.x * xv2; acc[4][3] += c1.x * xv3;
        acc[5][0] += c1.y * xv0; acc[5][1] += c1.y * xv1; acc[5][2] += c1.y * xv2; acc[5][3] += c1.y * xv3;
        acc[6][0] += c1.z * xv0; acc[6][1] += c1.z * xv1; acc[6][2] += c1.z * xv2; acc[6][3] += c1.z * xv3;
        acc[7][0] += c1.w * xv0; acc[7][1] += c1.w * xv1; acc[7][2] += c1.w * xv2; acc[7][3] += c1.w * xv3;
    }
    float xq0 = xxb[tid], xq1 = xxb[tid + 512], xq2 = xxb[tid + 1024], xq3 = xxb[tid + 1536];
    #pragma unroll
    for (int r = 0; r < 8; ++r) {
        dist[r][tid]        = fkey(fmaf(-2.f, acc[r][0], xq0));
        dist[r][tid + 512]  = fkey(fmaf(-2.f, acc[r][1], xq1));
        dist[r][tid + 1024] = fkey(fmaf(-2.f, acc[r][2], xq2));
        dist[r][tid + 1536] = fkey(fmaf(-2.f, acc[r][3], xq3));
    }
    __syncthreads();

    const int w = tid >> 6, lane = tid & 63;
    unsigned* drow = dist[w];
    int* outp = idx + ((long)b * Nn + n0 + w) * KK;

    auto scan2 = [&](u64& m1, u64& m2) {
        m1 = ~0ull; m2 = ~0ull;
        #pragma unroll
        for (int jj = 0; jj < 8; ++jj) {
            int j4 = (jj * 64 + lane) * 4;
            uint4 v = *(const uint4*)(drow + j4);
            u64 kk0 = ((u64)v.x << 32) | (unsigned)(j4 + 0);
            u64 kk1 = ((u64)v.y << 32) | (unsigned)(j4 + 1);
            u64 kk2 = ((u64)v.z << 32) | (unsigned)(j4 + 2);
            u64 kk3 = ((u64)v.w << 32) | (unsigned)(j4 + 3);
            u64 hi;
            hi = kk0 > m1 ? kk0 : m1; m1 = kk0 < m1 ? kk0 : m1; m2 = hi < m2 ? hi : m2;
            hi = kk1 > m1 ? kk1 : m1; m1 = kk1 < m1 ? kk1 : m1; m2 = hi < m2 ? hi : m2;
            hi = kk2 > m1 ? kk2 : m1; m1 = kk2 < m1 ? kk2 : m1; m2 = hi < m2 ? hi : m2;
            hi = kk3 > m1 ? kk3 : m1; m1 = kk3 < m1 ? kk3 : m1; m2 = hi < m2 ? hi : m2;
        }
    };

    u64 lm1, lm2;
    scan2(lm1, lm2);
    for (int k = 0; k < KK; ++k) {
        unsigned key = (unsigned)(lm1 >> 32);
        unsigned bk = key;
        #pragma unroll
        for (int s = 1; s < 64; s <<= 1) {
            unsigned ob = __shfl_xor(bk, s, 64);
            bk = ob < bk ? ob : bk;
        }
        u64 winners = __ballot(key == bk);
        int wl; int bi;
        if (__popcll(winners) == 1) {
            wl = (int)(__ffsll((unsigned long long)winners) - 1);
            bi = (int)__shfl((unsigned)lm1, wl, 64);
        } else {
            unsigned jc = (key == bk) ? (unsigned)lm1 : 0xFFFFFFFFu;
            unsigned bj = jc;
            #pragma unroll
            for (int s = 1; s < 64; s <<= 1) {
                unsigned oj = __shfl_xor(bj, s, 64);
                bj = oj < bj ? oj : bj;
            }
            winners = __ballot(key == bk && (unsigned)lm1 == bj);
            wl = (int)(__ffsll((unsigned long long)winners) - 1);
            bi = (int)bj;
        }
        if (lane == 0) outp[k] = bi;
        if (lane == wl) {
            drow[bi] = 0xFFFFFFFFu;
            if (lm2 != ~0ull) { lm1 = lm2; lm2 = ~0ull; }
            else scan2(lm1, lm2);
        }
    }
}

// ---------------- projection GEMM ----------------
template<int CIN, int CO2>
__global__ void __launch_bounds__(256)
proj_gemm(const float* __restrict__ x, long bst,
          const float* __restrict__ Wstk, float* __restrict__ Z) {
    const int tid = threadIdx.x;
    const int b  = blockIdx.x & 7;
    const int mt = (blockIdx.x >> 3) & 31;
    const int ot = blockIdx.x >> 8;
    const int mi = mt * 64 + (tid & 15) * 4;
    const int oj = ot * 64 + (tid >> 4) * 4;
    const float* xb = x + (long)b * bst + mi;

    float acc[4][4];
    #pragma unroll
    for (int r = 0; r < 4; ++r)
        #pragma unroll
        for (int j = 0; j < 4; ++j) acc[r][j] = 0.f;

    #pragma unroll 4
    for (int c = 0; c < CIN; ++c) {
        float4 xv = *(const float4*)(xb + (long)c * Nn);
        float4 wv = *(const float4*)(Wstk + (long)c * CO2 + oj);
        acc[0][0] += xv.x * wv.x; acc[0][1] += xv.x * wv.y; acc[0][2] += xv.x * wv.z; acc[0][3] += xv.x * wv.w;
        acc[1][0] += xv.y * wv.x; acc[1][1] += xv.y * wv.y; acc[1][2] += xv.y * wv.z; acc[1][3] += xv.y * wv.w;
        acc[2][0] += xv.z * wv.x; acc[2][1] += xv.z * wv.y; acc[2][2] += xv.z * wv.z; acc[2][3] += xv.z * wv.w;
        acc[3][0] += xv.w * wv.x; acc[3][1] += xv.w * wv.y; acc[3][2] += xv.w * wv.z; acc[3][3] += xv.w * wv.w;
    }
    float* Zb = Z + (long)b * 2048 * CO2;
    #pragma unroll
    for (int r = 0; r < 4; ++r) {
        float4 v = make_float4(acc[r][0], acc[r][1], acc[r][2], acc[r][3]);
        *(float4*)(Zb + (long)(mi + r) * CO2 + oj) = v;
    }
}

// ---------------- gather-max epilogue (also emits bf16 n-major copy) ----------------
template<int CO>
__global__ void __launch_bounds__(256)
gather_max(const float* __restrict__ Z, const int* __restrict__ idx,
           float* __restrict__ out, long obst,
           __hip_bfloat16* __restrict__ xbT, int coff) {
    constexpr int CO2 = 2 * CO;
    constexpr int VEC = CO / 64;
    __shared__ float tile[16][CO + 4];
    __shared__ int ji[16][KK];
    const int tid = threadIdx.x;
    const int b  = blockIdx.x & 7;
    const int n0 = (blockIdx.x >> 3) * 16;
    const float* Zb = Z + (long)b * 2048 * CO2;

    for (int t = tid; t < 16 * KK; t += 256) {
        int nn = t / KK, k = t - nn * KK;
        ji[nn][k] = idx[((long)b * Nn + n0 + nn) * KK + k];
    }
    __syncthreads();

    const int w = tid >> 6, lane = tid & 63;
    for (int i = 0; i < 4; ++i) {
        int nl = w * 4 + i, n = n0 + nl;
        float mx[VEC];
        #pragma unroll
        for (int v = 0; v < VEC; ++v) mx[v] = -FLT_MAX;
        for (int k = 0; k < KK; ++k) {
            int m = ji[nl][k];
            const float* zr = Zb + (long)m * CO2 + lane * VEC;
            #pragma unroll
            for (int v = 0; v < VEC; ++v) mx[v] = fmaxf(mx[v], zr[v]);
        }
        const float* zc = Zb + (long)n * CO2 + CO + lane * VEC;
        __hip_bfloat16* xr = xbT + ((long)b * 2048 + n) * 512 + coff + lane * VEC;
        #pragma unroll
        for (int v = 0; v < VEC; ++v) {
            float y = mx[v] + zc[v];
            y = y > 0.f ? y : SLOPE * y;
            tile[nl][lane * VEC + v] = y;
            xr[v] = __float2bfloat16(y);
        }
    }
    __syncthreads();

    for (int r = tid; r < CO * 4; r += 256) {
        int o = r >> 2, q = r & 3;
        float4 vv;
        vv.x = tile[q * 4 + 0][o];
        vv.y = tile[q * 4 + 1][o];
        vv.z = tile[q * 4 + 2][o];
        vv.w = tile[q * 4 + 3][o];
        *(float4*)(out + (long)b * obst + (long)o * Nn + n0 + q * 4) = vv;
    }
}

// ---------------- Global conv via bf16 MFMA, fused max-over-n ----------------
__global__ void __launch_bounds__(256)
global_mfma(const __hip_bfloat16* __restrict__ Wgb,
            const __hip_bfloat16* __restrict__ xbT,
            float* __restrict__ partial) {
    const int tid = threadIdx.x;
    const int w = tid >> 6, lane = tid & 63;
    const int lm = lane & 15, quad = lane >> 4;
    const int b  = blockIdx.x >> 7;
    const int ot = (blockIdx.x >> 3) & 15;
    const int nb = blockIdx.x & 7;
    const int o0 = ot * 64;
    const int nbw = nb * 256 + w * 64;

    const __hip_bfloat16* Arow = Wgb + (long)(o0 + lm) * 512 + quad * 8;
    const __hip_bfloat16* Brow = xbT + ((long)b * 2048 + nbw + lm) * 512 + quad * 8;

    f32x4 acc[4][4];
    #pragma unroll
    for (int mt = 0; mt < 4; ++mt)
        #pragma unroll
        for (int nt = 0; nt < 4; ++nt)
            acc[mt][nt] = (f32x4){0.f, 0.f, 0.f, 0.f};

    #pragma unroll 2
    for (int kk = 0; kk < 512; kk += 32) {
        bf16x8 a[4], bb[4];
        #pragma unroll
        for (int mt = 0; mt < 4; ++mt)
            a[mt] = *(const bf16x8*)(const void*)(Arow + (long)mt * 16 * 512 + kk);
        #pragma unroll
        for (int nt = 0; nt < 4; ++nt)
            bb[nt] = *(const bf16x8*)(const void*)(Brow + (long)nt * 16 * 512 + kk);
        #pragma unroll
        for (int mt = 0; mt < 4; ++mt)
            #pragma unroll
            for (int nt = 0; nt < 4; ++nt)
                acc[mt][nt] = __builtin_amdgcn_mfma_f32_16x16x32_bf16(
                    a[mt], bb[nt], acc[mt][nt], 0, 0, 0);
    }

    #pragma unroll
    for (int mt = 0; mt < 4; ++mt) {
        #pragma unroll
        for (int r = 0; r < 4; ++r) {
            float v = fmaxf(fmaxf(acc[mt][0][r], acc[mt][1][r]),
                            fmaxf(acc[mt][2][r], acc[mt][3][r]));
            #pragma unroll
            for (int s = 1; s < 16; s <<= 1)
                v = fmaxf(v, __shfl_xor(v, s, 16));
            if (lm == 0) {
                int o = o0 + mt * 16 + quad * 4 + r;
                partial[((long)b * 1024 + o) * NCH + nb * 4 + w] = v;
            }
        }
    }
}

// ---------------- final max over chunks + leaky ----------------
__global__ void gmax_kernel(const float* __restrict__ partial, float* __restrict__ out) {
    int i = blockIdx.x * 256 + threadIdx.x;
    float m = -FLT_MAX;
    #pragma unroll
    for (int j = 0; j < NCH; ++j) m = fmaxf(m, partial[(long)i * NCH + j]);
    out[i] = m > 0.f ? m : SLOPE * m;
}

extern "C" void kernel_launch(void* const* d_in, const int* in_sizes, int n_in,
                              void* d_out, int out_size, void* d_ws, size_t ws_size,
                              hipStream_t stream) {
    const float* x  = (const float*)d_in[0];
    const float* W1 = (const float*)d_in[1];
    const float* W2 = (const float*)d_in[2];
    const float* W3 = (const float*)d_in[3];
    const float* W4 = (const float*)d_in[4];
    const float* Wg = (const float*)d_in[5];
    float* out = (float*)d_out;

    float* ws = (float*)d_ws;
    float* xcat = ws;                                       // 8*512*2048 f32
    int*   idxb = (int*)(xcat + (long)BB * 512 * Nn);       // 8*2048*20 int
    float* part = (float*)(idxb + (long)BB * Nn * KK);      // 8*1024*NCH f32
    float* ws1  = part + (long)BB * 1024 * NCH;
    float* ws2  = ws1 + 2 * 3 * 64;
    float* ws3  = ws2 + 2 * 64 * 64;
    float* ws4  = ws3 + 2 * 64 * 128;
    __hip_bfloat16* Wgb = (__hip_bfloat16*)(ws4 + 2 * 128 * 256);  // 1024*512 bf16
    __hip_bfloat16* xbT = Wgb + (long)1024 * 512;                  // 8*2048*512 bf16
    float* xx = (float*)(xbT + (long)BB * Nn * 512);               // 8*2048 f32
    __hip_bfloat16* S = (__hip_bfloat16*)(xx + BB * Nn);           // 8*2048*256 bf16 (max)
    unsigned* Dkeys = (unsigned*)(S + (long)BB * Nn * 256);        // 4*2048*2048 u32
    float* Z = (float*)Dkeys;   // 8*2048*512 f32 aliases Dkeys (proj runs after select)

    const long XB = (long)512 * Nn;

    prep_kernel<<<(192 + 4096 + 8192 + 32768 + 1024 * 512 + 255) / 256, 256, 0, stream>>>(
        W1, W2, W3, W4, Wg, ws1, ws2, ws3, ws4, Wgb);

    const int knn_grid  = BB * 256;
    const int spl_grid  = BB * 32;
    const int sq_grid   = BB * Nn / 256;
    const int ep_grid   = (Nn / 16) * BB;
    const int gram_grid = 4 * 8 * 32;    // 4 batches x 8 ctiles x 32 jtiles
    const int sel_grid  = 4 * 512;       // 4 batches x 512 rowgroups

    // stage 1: x (C=3) -> xcat[0:64], xbT[:, 0:64)
    sqnorm_kernel<<<sq_grid, 256, 0, stream>>>(x, (long)3 * Nn, 3, xx);
    knn_kernel<3><<<knn_grid, 512, 0, stream>>>(x, (long)3 * Nn, xx, idxb);
    proj_gemm<3, 128><<<8 * 32 * 2, 256, 0, stream>>>(x, (long)3 * Nn, ws1, Z);
    gather_max<64><<<ep_grid, 256, 0, stream>>>(Z, idxb, xcat, XB, xbT, 0);
    // stage 2
    sqnorm_kernel<<<sq_grid, 256, 0, stream>>>(xcat, XB, 64, xx);
    split_kernel<64><<<spl_grid, 256, 0, stream>>>(xcat, XB, S);
    gram_gemm<64><<<gram_grid, 256, 0, stream>>>(S, xx, Dkeys, 0);
    knn_select<<<sel_grid, 256, 0, stream>>>(Dkeys, 0, idxb);
    gram_gemm<64><<<gram_grid, 256, 0, stream>>>(S, xx, Dkeys, 4);
    knn_select<<<sel_grid, 256, 0, stream>>>(Dkeys, 4, idxb);
    proj_gemm<64, 128><<<8 * 32 * 2, 256, 0, stream>>>(xcat, XB, ws2, Z);
    gather_max<64><<<ep_grid, 256, 0, stream>>>(Z, idxb, xcat + (long)64 * Nn, XB, xbT, 64);
    // stage 3
    sqnorm_kernel<<<sq_grid, 256, 0, stream>>>(xcat + (long)64 * Nn, XB, 64, xx);
    split_kernel<64><<<spl_grid, 256, 0, stream>>>(xcat + (long)64 * Nn, XB, S);
    gram_gemm<64><<<gram_grid, 256, 0, stream>>>(S, xx, Dkeys, 0);
    knn_select<<<sel_grid, 256, 0, stream>>>(Dkeys, 0, idxb);
    gram_gemm<64><<<gram_grid, 256, 0, stream>>>(S, xx, Dkeys, 4);
    knn_select<<<sel_grid, 256, 0, stream>>>(Dkeys, 4, idxb);
    proj_gemm<64, 256><<<8 * 32 * 4, 256, 0, stream>>>(xcat + (long)64 * Nn, XB, ws3, Z);
    gather_max<128><<<ep_grid, 256, 0, stream>>>(Z, idxb, xcat + (long)128 * Nn, XB, xbT, 128);
    // stage 4
    sqnorm_kernel<<<sq_grid, 256, 0, stream>>>(xcat + (long)128 * Nn, XB, 128, xx);
    split_kernel<128><<<spl_grid, 256, 0, stream>>>(xcat + (long)128 * Nn, XB, S);
    gram_gemm<128><<<gram_grid, 256, 0, stream>>>(S, xx, Dkeys, 0);
    knn_select<<<sel_grid, 256, 0, stream>>>(Dkeys, 0, idxb);
    gram_gemm<128><<<gram_grid, 256, 0, stream>>>(S, xx, Dkeys, 4);
    knn_select<<<sel_grid, 256, 0, stream>>>(Dkeys, 4, idxb);
    proj_gemm<128, 512><<<8 * 32 * 8, 256, 0, stream>>>(xcat + (long)128 * Nn, XB, ws4, Z);
    gather_max<256><<<ep_grid, 256, 0, stream>>>(Z, idxb, xcat + (long)256 * Nn, XB, xbT, 256);

    // global conv via MFMA (fused max) + final reduce
    global_mfma<<<BB * 16 * 8, 256, 0, stream>>>(Wgb, xbT, part);
    gmax_kernel<<<BB * 1024 / 256, 256, 0, stream>>>(part, out);
}

// Round 11
// 764.058 us; speedup vs baseline: 1.4416x; 1.0909x over previous
//
#include <hip/hip_runtime.h>
#include <hip/hip_bf16.h>
#include <cfloat>

#define Nn 2048
#define KK 20
#define BB 8
#define SLOPE 0.2f
#define NCH 32   // partial chunks in global conv (8 nblk x 4 waves)

typedef __bf16 bf16x8 __attribute__((ext_vector_type(8)));
typedef float f32x4 __attribute__((ext_vector_type(4)));
typedef unsigned long long u64;

// ---------------- fused prep: wstack W1..W4 + bf16(Wg) ----------------
// Wstk[c][o] = W[o][c]; Wstk[c][Co+o] = W[o][C+c] - W[o][c]
__device__ __forceinline__ void wstack_elem(const float* W, float* Wstk,
                                            int Co, int C, int i) {
    int o = i / C, c = i - o * C;
    float a = W[(long)o * 2 * C + c];
    float bb = W[(long)o * 2 * C + C + c];
    Wstk[(long)c * 2 * Co + o] = a;
    Wstk[(long)c * 2 * Co + Co + o] = bb - a;
}

__global__ void prep_kernel(const float* __restrict__ W1, const float* __restrict__ W2,
                            const float* __restrict__ W3, const float* __restrict__ W4,
                            const float* __restrict__ Wg,
                            float* __restrict__ ws1, float* __restrict__ ws2,
                            float* __restrict__ ws3, float* __restrict__ ws4,
                            __hip_bfloat16* __restrict__ Wgb) {
    int i = blockIdx.x * 256 + threadIdx.x;
    if (i < 192) { wstack_elem(W1, ws1, 64, 3, i); return; }
    i -= 192;
    if (i < 4096) { wstack_elem(W2, ws2, 64, 64, i); return; }
    i -= 4096;
    if (i < 8192) { wstack_elem(W3, ws3, 128, 64, i); return; }
    i -= 8192;
    if (i < 32768) { wstack_elem(W4, ws4, 256, 128, i); return; }
    i -= 32768;
    if (i < 1024 * 512) Wgb[i] = __float2bfloat16(Wg[i]);
}

// order-preserving float-bits -> u32 map (works for negatives)
__device__ __forceinline__ unsigned fkey(float f) {
    unsigned u = __float_as_uint(f);
    return u ^ (((unsigned)((int)u >> 31)) | 0x80000000u);
}

// ---------------- KNN: 8 rows per block, 512 threads (R6 structure) ----------------
// dist order == xx_j - 2*dot(x_n, x_j)  (per-row const xx_n dropped: order-invariant)
template<int C>
__global__ void __launch_bounds__(512)
knn_kernel(const float* __restrict__ x, long bstride, int* __restrict__ idx) {
    __shared__ unsigned dist[8][Nn];   // XOR-mapped float keys; 64 KB exactly
    const int tid = threadIdx.x;
    const int b  = blockIdx.x >> 8;         // Nn/8 = 256 blocks per b
    const int n0 = (blockIdx.x & 255) * 8;
    const float* xb = x + (long)b * bstride;

    // distance phase: thread owns j = q*512 + tid, q = 0..3
    float acc[8][4];
    #pragma unroll
    for (int r = 0; r < 8; ++r)
        #pragma unroll
        for (int q = 0; q < 4; ++q) acc[r][q] = 0.f;
    float sq[4] = {0.f, 0.f, 0.f, 0.f};

    #pragma unroll 4
    for (int c = 0; c < C; ++c) {
        const float* xp = xb + (long)c * Nn;
        float xv0 = xp[tid];
        float xv1 = xp[tid + 512];
        float xv2 = xp[tid + 1024];
        float xv3 = xp[tid + 1536];
        float4 c0 = *(const float4*)(xp + n0);      // block-uniform -> scalar pipe
        float4 c1 = *(const float4*)(xp + n0 + 4);
        sq[0] += xv0 * xv0; sq[1] += xv1 * xv1; sq[2] += xv2 * xv2; sq[3] += xv3 * xv3;
        acc[0][0] += c0.x * xv0; acc[0][1] += c0.x * xv1; acc[0][2] += c0.x * xv2; acc[0][3] += c0.x * xv3;
        acc[1][0] += c0.y * xv0; acc[1][1] += c0.y * xv1; acc[1][2] += c0.y * xv2; acc[1][3] += c0.y * xv3;
        acc[2][0] += c0.z * xv0; acc[2][1] += c0.z * xv1; acc[2][2] += c0.z * xv2; acc[2][3] += c0.z * xv3;
        acc[3][0] += c0.w * xv0; acc[3][1] += c0.w * xv1; acc[3][2] += c0.w * xv2; acc[3][3] += c0.w * xv3;
        acc[4][0] += c1.x * xv0; acc[4][1] += c1.x * xv1; acc[4][2] += c1.x * xv2; acc[4][3] += c1.x * xv3;
        acc[5][0] += c1.y * xv0; acc[5][1] += c1.y * xv1; acc[5][2] += c1.y * xv2; acc[5][3] += c1.y * xv3;
        acc[6][0] += c1.z * xv0; acc[6][1] += c1.z * xv1; acc[6][2] += c1.z * xv2; acc[6][3] += c1.z * xv3;
        acc[7][0] += c1.w * xv0; acc[7][1] += c1.w * xv1; acc[7][2] += c1.w * xv2; acc[7][3] += c1.w * xv3;
    }
    #pragma unroll
    for (int r = 0; r < 8; ++r) {
        #pragma unroll
        for (int q = 0; q < 4; ++q) {
            float d = fmaf(-2.f, acc[r][q], sq[q]);
            dist[r][q * 512 + tid] = fkey(d);
        }
    }
    __syncthreads();

    // selection: wave w owns row w; lazy per-lane top-2 in registers.
    // Per round: u32 min butterfly + ballot winner-lane (+ exact lowest-j tie-break).
    const int w = tid >> 6, lane = tid & 63;
    unsigned* drow = dist[w];
    int* outp = idx + ((long)b * Nn + n0 + w) * KK;

    auto scan2 = [&](u64& m1, u64& m2) {
        m1 = ~0ull; m2 = ~0ull;
        #pragma unroll
        for (int jj = 0; jj < 8; ++jj) {
            int j4 = (jj * 64 + lane) * 4;
            uint4 v = *(const uint4*)(drow + j4);
            u64 kk0 = ((u64)v.x << 32) | (unsigned)(j4 + 0);
            u64 kk1 = ((u64)v.y << 32) | (unsigned)(j4 + 1);
            u64 kk2 = ((u64)v.z << 32) | (unsigned)(j4 + 2);
            u64 kk3 = ((u64)v.w << 32) | (unsigned)(j4 + 3);
            u64 hi;
            hi = kk0 > m1 ? kk0 : m1; m1 = kk0 < m1 ? kk0 : m1; m2 = hi < m2 ? hi : m2;
            hi = kk1 > m1 ? kk1 : m1; m1 = kk1 < m1 ? kk1 : m1; m2 = hi < m2 ? hi : m2;
            hi = kk2 > m1 ? kk2 : m1; m1 = kk2 < m1 ? kk2 : m1; m2 = hi < m2 ? hi : m2;
            hi = kk3 > m1 ? kk3 : m1; m1 = kk3 < m1 ? kk3 : m1; m2 = hi < m2 ? hi : m2;
        }
    };

    u64 lm1, lm2;
    scan2(lm1, lm2);
    for (int k = 0; k < KK; ++k) {
        unsigned key = (unsigned)(lm1 >> 32);
        unsigned bk = key;
        #pragma unroll
        for (int s = 1; s < 64; s <<= 1) {
            unsigned ob = __shfl_xor(bk, s, 64);
            bk = ob < bk ? ob : bk;
        }
        u64 winners = __ballot(key == bk);
        int wl; int bi;
        if (__popcll(winners) == 1) {
            wl = (int)(__ffsll((unsigned long long)winners) - 1);
            bi = (int)__shfl((unsigned)lm1, wl, 64);
        } else {
            // exact tie-break: lowest j among equal keys (rare path)
            unsigned jc = (key == bk) ? (unsigned)lm1 : 0xFFFFFFFFu;
            unsigned bj = jc;
            #pragma unroll
            for (int s = 1; s < 64; s <<= 1) {
                unsigned oj = __shfl_xor(bj, s, 64);
                bj = oj < bj ? oj : bj;
            }
            winners = __ballot(key == bk && (unsigned)lm1 == bj);
            wl = (int)(__ffsll((unsigned long long)winners) - 1);
            bi = (int)bj;
        }
        if (lane == 0) outp[k] = bi;
        if (lane == wl) {
            drow[bi] = 0xFFFFFFFFu;  // consumed sentinel
            if (lm2 != ~0ull) { lm1 = lm2; lm2 = ~0ull; }
            else scan2(lm1, lm2);    // rare: lane's 3rd+ win since last refill
        }
    }
}

// ---------------- projection GEMM: Z[m][0..2Co) = sum_c x[c][m] * Wstk[c][.] ----
template<int CIN, int CO2>
__global__ void __launch_bounds__(256)
proj_gemm(const float* __restrict__ x, long bst,
          const float* __restrict__ Wstk, float* __restrict__ Z) {
    const int tid = threadIdx.x;
    const int b  = blockIdx.x & 7;
    const int mt = (blockIdx.x >> 3) & 31;
    const int ot = blockIdx.x >> 8;
    const int mi = mt * 64 + (tid & 15) * 4;
    const int oj = ot * 64 + (tid >> 4) * 4;
    const float* xb = x + (long)b * bst + mi;

    float acc[4][4];
    #pragma unroll
    for (int r = 0; r < 4; ++r)
        #pragma unroll
        for (int j = 0; j < 4; ++j) acc[r][j] = 0.f;

    #pragma unroll 4
    for (int c = 0; c < CIN; ++c) {
        float4 xv = *(const float4*)(xb + (long)c * Nn);
        float4 wv = *(const float4*)(Wstk + (long)c * CO2 + oj);
        acc[0][0] += xv.x * wv.x; acc[0][1] += xv.x * wv.y; acc[0][2] += xv.x * wv.z; acc[0][3] += xv.x * wv.w;
        acc[1][0] += xv.y * wv.x; acc[1][1] += xv.y * wv.y; acc[1][2] += xv.y * wv.z; acc[1][3] += xv.y * wv.w;
        acc[2][0] += xv.z * wv.x; acc[2][1] += xv.z * wv.y; acc[2][2] += xv.z * wv.z; acc[2][3] += xv.z * wv.w;
        acc[3][0] += xv.w * wv.x; acc[3][1] += xv.w * wv.y; acc[3][2] += xv.w * wv.z; acc[3][3] += xv.w * wv.w;
    }
    float* Zb = Z + (long)b * 2048 * CO2;
    #pragma unroll
    for (int r = 0; r < 4; ++r) {
        float4 v = make_float4(acc[r][0], acc[r][1], acc[r][2], acc[r][3]);
        *(float4*)(Zb + (long)(mi + r) * CO2 + oj) = v;
    }
}

// ---------------- gather-max epilogue (also emits bf16 n-major copy) ----------------
template<int CO>
__global__ void __launch_bounds__(256)
gather_max(const float* __restrict__ Z, const int* __restrict__ idx,
           float* __restrict__ out, long obst,
           __hip_bfloat16* __restrict__ xbT, int coff) {
    constexpr int CO2 = 2 * CO;
    constexpr int VEC = CO / 64;
    __shared__ float tile[16][CO + 4];
    __shared__ int ji[16][KK];
    const int tid = threadIdx.x;
    const int b  = blockIdx.x & 7;
    const int n0 = (blockIdx.x >> 3) * 16;
    const float* Zb = Z + (long)b * 2048 * CO2;

    for (int t = tid; t < 16 * KK; t += 256) {
        int nn = t / KK, k = t - nn * KK;
        ji[nn][k] = idx[((long)b * Nn + n0 + nn) * KK + k];
    }
    __syncthreads();

    const int w = tid >> 6, lane = tid & 63;
    for (int i = 0; i < 4; ++i) {
        int nl = w * 4 + i, n = n0 + nl;
        float mx[VEC];
        #pragma unroll
        for (int v = 0; v < VEC; ++v) mx[v] = -FLT_MAX;
        for (int k = 0; k < KK; ++k) {
            int m = ji[nl][k];
            const float* zr = Zb + (long)m * CO2 + lane * VEC;
            #pragma unroll
            for (int v = 0; v < VEC; ++v) mx[v] = fmaxf(mx[v], zr[v]);
        }
        const float* zc = Zb + (long)n * CO2 + CO + lane * VEC;
        __hip_bfloat16* xr = xbT + ((long)b * 2048 + n) * 512 + coff + lane * VEC;
        #pragma unroll
        for (int v = 0; v < VEC; ++v) {
            float y = mx[v] + zc[v];
            y = y > 0.f ? y : SLOPE * y;
            tile[nl][lane * VEC + v] = y;
            xr[v] = __float2bfloat16(y);
        }
    }
    __syncthreads();

    for (int r = tid; r < CO * 4; r += 256) {
        int o = r >> 2, q = r & 3;
        float4 vv;
        vv.x = tile[q * 4 + 0][o];
        vv.y = tile[q * 4 + 1][o];
        vv.z = tile[q * 4 + 2][o];
        vv.w = tile[q * 4 + 3][o];
        *(float4*)(out + (long)b * obst + (long)o * Nn + n0 + q * 4) = vv;
    }
}

// ---------------- Global conv via bf16 MFMA, fused max-over-n ----------------
__global__ void __launch_bounds__(256)
global_mfma(const __hip_bfloat16* __restrict__ Wgb,   // [1024][512]
            const __hip_bfloat16* __restrict__ xbT,   // [B][2048][512]
            float* __restrict__ partial) {            // [B][1024][NCH]
    const int tid = threadIdx.x;
    const int w = tid >> 6, lane = tid & 63;
    const int lm = lane & 15, quad = lane >> 4;
    const int b  = blockIdx.x >> 7;
    const int ot = (blockIdx.x >> 3) & 15;
    const int nb = blockIdx.x & 7;
    const int o0 = ot * 64;
    const int nbw = nb * 256 + w * 64;

    const __hip_bfloat16* Arow = Wgb + (long)(o0 + lm) * 512 + quad * 8;
    const __hip_bfloat16* Brow = xbT + ((long)b * 2048 + nbw + lm) * 512 + quad * 8;

    f32x4 acc[4][4];
    #pragma unroll
    for (int mt = 0; mt < 4; ++mt)
        #pragma unroll
        for (int nt = 0; nt < 4; ++nt)
            acc[mt][nt] = (f32x4){0.f, 0.f, 0.f, 0.f};

    #pragma unroll 2
    for (int kk = 0; kk < 512; kk += 32) {
        bf16x8 a[4], bb[4];
        #pragma unroll
        for (int mt = 0; mt < 4; ++mt)
            a[mt] = *(const bf16x8*)(const void*)(Arow + (long)mt * 16 * 512 + kk);
        #pragma unroll
        for (int nt = 0; nt < 4; ++nt)
            bb[nt] = *(const bf16x8*)(const void*)(Brow + (long)nt * 16 * 512 + kk);
        #pragma unroll
        for (int mt = 0; mt < 4; ++mt)
            #pragma unroll
            for (int nt = 0; nt < 4; ++nt)
                acc[mt][nt] = __builtin_amdgcn_mfma_f32_16x16x32_bf16(
                    a[mt], bb[nt], acc[mt][nt], 0, 0, 0);
    }

    // D mapping: col(n) = lane&15, row(m) = quad*4 + reg
    #pragma unroll
    for (int mt = 0; mt < 4; ++mt) {
        #pragma unroll
        for (int r = 0; r < 4; ++r) {
            float v = fmaxf(fmaxf(acc[mt][0][r], acc[mt][1][r]),
                            fmaxf(acc[mt][2][r], acc[mt][3][r]));
            #pragma unroll
            for (int s = 1; s < 16; s <<= 1)
                v = fmaxf(v, __shfl_xor(v, s, 16));
            if (lm == 0) {
                int o = o0 + mt * 16 + quad * 4 + r;
                partial[((long)b * 1024 + o) * NCH + nb * 4 + w] = v;
            }
        }
    }
}

// ---------------- final max over chunks + leaky ----------------
__global__ void gmax_kernel(const float* __restrict__ partial, float* __restrict__ out) {
    int i = blockIdx.x * 256 + threadIdx.x;   // 0..8191
    float m = -FLT_MAX;
    #pragma unroll
    for (int j = 0; j < NCH; ++j) m = fmaxf(m, partial[(long)i * NCH + j]);
    out[i] = m > 0.f ? m : SLOPE * m;
}

extern "C" void kernel_launch(void* const* d_in, const int* in_sizes, int n_in,
                              void* d_out, int out_size, void* d_ws, size_t ws_size,
                              hipStream_t stream) {
    const float* x  = (const float*)d_in[0];
    const float* W1 = (const float*)d_in[1];   // [64][6]
    const float* W2 = (const float*)d_in[2];   // [64][128]
    const float* W3 = (const float*)d_in[3];   // [128][128]
    const float* W4 = (const float*)d_in[4];   // [256][256]
    const float* Wg = (const float*)d_in[5];   // [1024][512]
    float* out = (float*)d_out;

    float* ws = (float*)d_ws;
    float* xcat = ws;                                       // 8*512*2048 f32
    int*   idxb = (int*)(xcat + (long)BB * 512 * Nn);       // 8*2048*20 int
    float* part = (float*)(idxb + (long)BB * Nn * KK);      // 8*1024*NCH f32
    float* ws1  = part + (long)BB * 1024 * NCH;             // 3*128
    float* ws2  = ws1 + 3 * 128;                            // 64*128
    float* ws3  = ws2 + 64 * 128;                           // 64*256
    float* ws4  = ws3 + 64 * 256;                           // 128*512
    __hip_bfloat16* Wgb = (__hip_bfloat16*)(ws4 + 128 * 512);   // 1024*512 bf16
    __hip_bfloat16* xbT = Wgb + (long)1024 * 512;               // 8*2048*512 bf16
    float* Z    = (float*)(xbT + (long)BB * Nn * 512);          // 8*2048*512 f32 (max 1024)

    const long XB = (long)512 * Nn;   // xcat batch stride

    prep_kernel<<<(192 + 4096 + 8192 + 32768 + 1024 * 512 + 255) / 256, 256, 0, stream>>>(
        W1, W2, W3, W4, Wg, ws1, ws2, ws3, ws4, Wgb);

    const int knn_grid = BB * 256;         // 2048 blocks, 512 threads
    const int ep_grid  = (Nn / 16) * BB;   // 1024

    // stage 1: x (C=3) -> xcat[0:64], xbT[:, 0:64)
    knn_kernel<3><<<knn_grid, 512, 0, stream>>>(x, (long)3 * Nn, idxb);
    proj_gemm<3, 128><<<8 * 32 * 2, 256, 0, stream>>>(x, (long)3 * Nn, ws1, Z);
    gather_max<64><<<ep_grid, 256, 0, stream>>>(Z, idxb, xcat, XB, xbT, 0);
    // stage 2
    knn_kernel<64><<<knn_grid, 512, 0, stream>>>(xcat, XB, idxb);
    proj_gemm<64, 128><<<8 * 32 * 2, 256, 0, stream>>>(xcat, XB, ws2, Z);
    gather_max<64><<<ep_grid, 256, 0, stream>>>(Z, idxb, xcat + (long)64 * Nn, XB, xbT, 64);
    // stage 3
    knn_kernel<64><<<knn_grid, 512, 0, stream>>>(xcat + (long)64 * Nn, XB, idxb);
    proj_gemm<64, 256><<<8 * 32 * 4, 256, 0, stream>>>(xcat + (long)64 * Nn, XB, ws3, Z);
    gather_max<128><<<ep_grid, 256, 0, stream>>>(Z, idxb, xcat + (long)128 * Nn, XB, xbT, 128);
    // stage 4
    knn_kernel<128><<<knn_grid, 512, 0, stream>>>(xcat + (long)128 * Nn, XB, idxb);
    proj_gemm<128, 512><<<8 * 32 * 8, 256, 0, stream>>>(xcat + (long)128 * Nn, XB, ws4, Z);
    gather_max<256><<<ep_grid, 256, 0, stream>>>(Z, idxb, xcat + (long)256 * Nn, XB, xbT, 256);

    // global conv via MFMA (fused max) + final reduce
    global_mfma<<<BB * 16 * 8, 256, 0, stream>>>(Wgb, xbT, part);
    gmax_kernel<<<BB * 1024 / 256, 256, 0, stream>>>(part, out);
}